// Round 5
// baseline (30.857 us; speedup 1.0000x reference)
//
#include <hip/hip_runtime.h>
#include <math.h>

#define BS    64
#define NPTS  10000
#define D     128
#define MM    16
#define SG    1000
#define NPART 4              // blocks per batch
#define ROWS  (SG / NPART)   // 250 rows per block
#define ROWG  32             // 1024 threads = 32 row-groups x 32 lanes
#define QS    8

__device__ __forceinline__ float gelu_f(float x) {
    float x3 = x * x * x;
    return 0.5f * x * (1.0f + tanhf(0.7978845608028654f * (x + 0.044715f * x3)));
}

__device__ __forceinline__ void st_dev(float* p, float v) {
    __hip_atomic_store(p, v, __ATOMIC_RELAXED, __HIP_MEMORY_SCOPE_AGENT);
}
__device__ __forceinline__ float ld_dev(const float* p) {
    return __hip_atomic_load(p, __ATOMIC_RELAXED, __HIP_MEMORY_SCOPE_AGENT);
}

__global__ __launch_bounds__(1024) void fused_kernel(
    const float* __restrict__ node_emb, const int* __restrict__ sg_idx,
    const float* __restrict__ graph_emb, const float* __restrict__ meta,
    const float* __restrict__ sg_w1, const float* __restrict__ sg_b1,
    const float* __restrict__ sg_g,  const float* __restrict__ sg_bt,
    const float* __restrict__ sg_w2, const float* __restrict__ sg_b2,
    const float* __restrict__ mf_w1, const float* __restrict__ mf_b1,
    const float* __restrict__ mf_g,  const float* __restrict__ mf_bt,
    const float* __restrict__ mf_w2, const float* __restrict__ mf_b2,
    const float* __restrict__ cx_w1, const float* __restrict__ cx_b1,
    const float* __restrict__ cx_w2, const float* __restrict__ cx_b2,
    int* __restrict__ cnt,            // [BS], zeroed by memset each call
    float* __restrict__ ws_sum,       // [BS][NPART-1][D]
    float* __restrict__ ws_max,       // [BS][NPART-1][D]
    float* __restrict__ out)
{
    const int b    = blockIdx.x & (BS - 1);
    const int part = blockIdx.x >> 6;          // 0 = consumer, 1..3 = helpers
    const int t    = threadIdx.x;

    __shared__ int   idx_lds[256];
    __shared__ float ssum[ROWG][D];    // 16 KB
    __shared__ float smax[ROWG][D];    // 16 KB
    __shared__ float xbuf[2 * D];
    __shared__ float pbuf[QS][D];
    __shared__ float hbufA[D];
    __shared__ float hbufB[D];
    __shared__ float red_a[D], red_b[D], red_c[D], red_d[D];
    __shared__ float stats[4];

    // ---- stage this block's 250 indices
    if (t < ROWS) idx_lds[t] = sg_idx[b * SG + part * ROWS + t];
    __syncthreads();

    // ---- gather + per-group pool
    {
        const int g = t >> 5;
        const int c = t & 31;
        const float* __restrict__ base = node_emb + (size_t)b * NPTS * D;

        float4 s = make_float4(0.f, 0.f, 0.f, 0.f);
        float4 m = make_float4(-INFINITY, -INFINITY, -INFINITY, -INFINITY);

        #pragma unroll 4
        for (int j = g; j < ROWS; j += ROWG) {
            int id = idx_lds[j];
            float4 v = *(const float4*)(base + (size_t)id * D + (c << 2));
            float msk = (id != 0) ? 1.f : 0.f;   // node_emb[:,0] == 0 sentinel
            v.x *= msk; v.y *= msk; v.z *= msk; v.w *= msk;
            s.x += v.x; s.y += v.y; s.z += v.z; s.w += v.w;
            m.x = fmaxf(m.x, v.x); m.y = fmaxf(m.y, v.y);
            m.z = fmaxf(m.z, v.z); m.w = fmaxf(m.w, v.w);
        }
        *(float4*)&ssum[g][c * 4] = s;
        *(float4*)&smax[g][c * 4] = m;
    }
    __syncthreads();

    const int q = t >> 7;    // 0..7
    const int d = t & 127;

    // ---- block tree-reduce 32 row-groups -> [sum|max](128)
    {
        float rs = ssum[q * 4 + 0][d] + ssum[q * 4 + 1][d]
                 + ssum[q * 4 + 2][d] + ssum[q * 4 + 3][d];
        float rm = fmaxf(fmaxf(smax[q * 4 + 0][d], smax[q * 4 + 1][d]),
                         fmaxf(smax[q * 4 + 2][d], smax[q * 4 + 3][d]));
        __syncthreads();
        ssum[q][d] = rs;
        smax[q][d] = rm;
        __syncthreads();
        if (q == 0) {
            float fs = 0.f;
            #pragma unroll
            for (int r = 0; r < QS; ++r) fs += ssum[r][d];
            if (part == 0) xbuf[d] = fs;
            else           st_dev(&ws_sum[(b * (NPART - 1) + part - 1) * D + d], fs);
        } else if (q == 1) {
            float fm = -INFINITY;
            #pragma unroll
            for (int r = 0; r < QS; ++r) fm = fmaxf(fm, smax[r][d]);
            if (part == 0) xbuf[D + d] = fm;
            else           st_dev(&ws_max[(b * (NPART - 1) + part - 1) * D + d], fm);
        }
        __syncthreads();
    }

    if (part != 0) {   // helper: publish and exit
        if (t == 0)
            __hip_atomic_fetch_add(&cnt[b], 1, __ATOMIC_RELEASE, __HIP_MEMORY_SCOPE_AGENT);
        return;
    }

    // ---- consumer: wait for 3 helpers (all 256 blocks co-resident -> no deadlock)
    if (t == 0) {
        long guard = 0;
        while (__hip_atomic_load(&cnt[b], __ATOMIC_ACQUIRE, __HIP_MEMORY_SCOPE_AGENT)
                   < NPART - 1 && ++guard < 200000000L) {}
    }
    __syncthreads();

    // combine helper partials
    if (q == 0) {
        float fs = xbuf[d];
        #pragma unroll
        for (int h = 0; h < NPART - 1; ++h)
            fs += ld_dev(&ws_sum[(b * (NPART - 1) + h) * D + d]);
        xbuf[d] = fs;
    } else if (q == 1) {
        float fm = xbuf[D + d];
        #pragma unroll
        for (int h = 0; h < NPART - 1; ++h)
            fm = fmaxf(fm, ld_dev(&ws_max[(b * (NPART - 1) + h) * D + d]));
        xbuf[D + d] = fm;
    }
    __syncthreads();

    // ---- GEMV1 for sg (q<4) and mf (q>=4) in parallel
    {
        float acc = 0.f;
        if (q < 4) {
            const int k0 = q * 64;
            #pragma unroll 8
            for (int kk = 0; kk < 64; ++kk)
                acc = fmaf(xbuf[k0 + kk], sg_w1[(k0 + kk) * D + d], acc);
        } else {
            const int k0 = (q - 4) * 4;
            #pragma unroll
            for (int kk = 0; kk < 4; ++kk)
                acc = fmaf(meta[b * MM + k0 + kk], mf_w1[(k0 + kk) * D + d], acc);
        }
        pbuf[q][d] = acc;
        __syncthreads();
    }

    // ---- combine + fused LN (sum & sumsq in one pass), both branches parallel
    float h_sg = 0.f, h_mf = 0.f;
    if (q == 0) {
        h_sg = pbuf[0][d] + pbuf[1][d] + pbuf[2][d] + pbuf[3][d] + sg_b1[d];
        red_a[d] = h_sg; red_b[d] = h_sg * h_sg;
    } else if (q == 1) {
        h_mf = pbuf[4][d] + pbuf[5][d] + pbuf[6][d] + pbuf[7][d] + mf_b1[d];
        red_c[d] = h_mf; red_d[d] = h_mf * h_mf;
    }
    __syncthreads();
    if (t < 64) {
        float v1 = red_a[t] + red_a[t + 64];
        float v2 = red_b[t] + red_b[t + 64];
        #pragma unroll
        for (int off = 32; off; off >>= 1) {
            v1 += __shfl_xor(v1, off, 64);
            v2 += __shfl_xor(v2, off, 64);
        }
        if (t == 0) { stats[0] = v1 * (1.f / D); stats[1] = v2 * (1.f / D); }
    } else if (t < 128) {
        const int l = t - 64;
        float v1 = red_c[l] + red_c[l + 64];
        float v2 = red_d[l] + red_d[l + 64];
        #pragma unroll
        for (int off = 32; off; off >>= 1) {
            v1 += __shfl_xor(v1, off, 64);
            v2 += __shfl_xor(v2, off, 64);
        }
        if (l == 0) { stats[2] = v1 * (1.f / D); stats[3] = v2 * (1.f / D); }
    }
    __syncthreads();
    if (q == 0) {
        float mu = stats[0], var = stats[1] - mu * mu;
        hbufA[d] = gelu_f((h_sg - mu) * rsqrtf(var + 1e-5f) * sg_g[d] + sg_bt[d]);
    } else if (q == 1) {
        float mu = stats[2], var = stats[3] - mu * mu;
        hbufB[d] = gelu_f((h_mf - mu) * rsqrtf(var + 1e-5f) * mf_g[d] + mf_bt[d]);
    }
    __syncthreads();

    // ---- GEMV2 for sg (q<4) and mf (q>=4) in parallel
    {
        float acc = 0.f;
        if (q < 4) {
            const int k0 = q * 32;
            #pragma unroll 8
            for (int kk = 0; kk < 32; ++kk)
                acc = fmaf(hbufA[k0 + kk], sg_w2[(k0 + kk) * D + d], acc);
        } else {
            const int k0 = (q - 4) * 32;
            #pragma unroll 8
            for (int kk = 0; kk < 32; ++kk)
                acc = fmaf(hbufB[k0 + kk], mf_w2[(k0 + kk) * D + d], acc);
        }
        pbuf[q][d] = acc;
        __syncthreads();
        if (q == 0) {
            float sg = sg_b2[d] + mf_b2[d];
            #pragma unroll
            for (int r = 0; r < QS; ++r) sg += pbuf[r][d];
            out[b * D + d] = sg;
            xbuf[d] = sg;
        } else if (q == 1) {
            xbuf[D + d] = graph_emb[b * D + d];
        }
        __syncthreads();
    }

    // ---- cx GEMV1 (8-way) -> GELU
    {
        float acc = 0.f;
        const int k0 = q * 32;
        #pragma unroll 8
        for (int kk = 0; kk < 32; ++kk)
            acc = fmaf(xbuf[k0 + kk], cx_w1[(k0 + kk) * D + d], acc);
        pbuf[q][d] = acc;
        __syncthreads();
        if (q == 0) {
            float h = cx_b1[d];
            #pragma unroll
            for (int r = 0; r < QS; ++r) h += pbuf[r][d];
            hbufA[d] = gelu_f(h);
        }
        __syncthreads();
    }

    // ---- cx GEMV2 (8-way) -> ctxt output
    {
        float acc = 0.f;
        const int k0 = q * 16;
        #pragma unroll 8
        for (int kk = 0; kk < 16; ++kk)
            acc = fmaf(hbufA[k0 + kk], cx_w2[(k0 + kk) * D + d], acc);
        pbuf[q][d] = acc;
        __syncthreads();
        if (q == 0) {
            float o = cx_b2[d];
            #pragma unroll
            for (int r = 0; r < QS; ++r) o += pbuf[r][d];
            out[BS * D + b * D + d] = o;
        }
    }
}

extern "C" void kernel_launch(void* const* d_in, const int* in_sizes, int n_in,
                              void* d_out, int out_size, void* d_ws, size_t ws_size,
                              hipStream_t stream) {
    const float* node_emb  = (const float*)d_in[0];
    const float* graph_emb = (const float*)d_in[1];
    const int*   sg_idx    = (const int*)d_in[2];
    const float* meta      = (const float*)d_in[3];
    const float* sg_w1 = (const float*)d_in[4];
    const float* sg_b1 = (const float*)d_in[5];
    const float* sg_g  = (const float*)d_in[6];
    const float* sg_bt = (const float*)d_in[7];
    const float* sg_w2 = (const float*)d_in[8];
    const float* sg_b2 = (const float*)d_in[9];
    const float* mf_w1 = (const float*)d_in[10];
    const float* mf_b1 = (const float*)d_in[11];
    const float* mf_g  = (const float*)d_in[12];
    const float* mf_bt = (const float*)d_in[13];
    const float* mf_w2 = (const float*)d_in[14];
    const float* mf_b2 = (const float*)d_in[15];
    const float* cx_w1 = (const float*)d_in[16];
    const float* cx_b1 = (const float*)d_in[17];
    const float* cx_w2 = (const float*)d_in[18];
    const float* cx_b2 = (const float*)d_in[19];

    float* out = (float*)d_out;
    // ws layout: [0,256)B counters; then sum partials; then max partials
    int*   cnt    = (int*)d_ws;
    float* ws_sum = (float*)((char*)d_ws + 1024);
    float* ws_max = ws_sum + BS * (NPART - 1) * D;

    hipMemsetAsync(d_ws, 0, 256, stream);   // zero the per-batch counters each call
    fused_kernel<<<BS * NPART, 1024, 0, stream>>>(node_emb, sg_idx, graph_emb, meta,
        sg_w1, sg_b1, sg_g, sg_bt, sg_w2, sg_b2,
        mf_w1, mf_b1, mf_g, mf_bt, mf_w2, mf_b2,
        cx_w1, cx_b1, cx_w2, cx_b2, cnt, ws_sum, ws_max, out);
}

// Round 6
// 21.732 us; speedup vs baseline: 1.4199x; 1.4199x over previous
//
#include <hip/hip_runtime.h>
#include <math.h>

#define BS    64
#define NPTS  10000
#define D     128
#define MM    16
#define SG    1000
#define SPLIT 8              // pool blocks per batch
#define ROWS  (SG / SPLIT)   // 125 rows per pool block
#define PGRP  16             // 512 threads = 16 row-groups x 32 lanes
#define QS    8

__device__ __forceinline__ float gelu_f(float x) {
    float x3 = x * x * x;
    return 0.5f * x * (1.0f + tanhf(0.7978845608028654f * (x + 0.044715f * x3)));
}

__global__ __launch_bounds__(512) void pool_kernel(
    const float* __restrict__ node_emb, const int* __restrict__ sg_idx,
    float* __restrict__ ws_sum, float* __restrict__ ws_max)
{
    const int b  = blockIdx.x >> 3;
    const int sp = blockIdx.x & (SPLIT - 1);
    const int t  = threadIdx.x;

    __shared__ int   idx_lds[ROWS];
    __shared__ float ssum[PGRP][D];   // 8 KB
    __shared__ float smax[PGRP][D];   // 8 KB

    if (t < ROWS) idx_lds[t] = sg_idx[b * SG + sp * ROWS + t];
    __syncthreads();

    {
        const int g = t >> 5;    // 0..15
        const int c = t & 31;
        const float* __restrict__ base = node_emb + (size_t)b * NPTS * D;

        float4 s = make_float4(0.f, 0.f, 0.f, 0.f);
        float4 m = make_float4(-INFINITY, -INFINITY, -INFINITY, -INFINITY);

        #pragma unroll 4
        for (int j = g; j < ROWS; j += PGRP) {
            int id = idx_lds[j];
            float4 v = *(const float4*)(base + (size_t)id * D + (c << 2));
            float msk = (id != 0) ? 1.f : 0.f;   // node_emb[:,0] == 0 sentinel
            v.x *= msk; v.y *= msk; v.z *= msk; v.w *= msk;
            s.x += v.x; s.y += v.y; s.z += v.z; s.w += v.w;
            m.x = fmaxf(m.x, v.x); m.y = fmaxf(m.y, v.y);
            m.z = fmaxf(m.z, v.z); m.w = fmaxf(m.w, v.w);
        }
        *(float4*)&ssum[g][c * 4] = s;
        *(float4*)&smax[g][c * 4] = m;
    }
    __syncthreads();

    const int q = t >> 7;    // 0..3
    const int d = t & 127;

    float rs = ssum[q * 4 + 0][d] + ssum[q * 4 + 1][d]
             + ssum[q * 4 + 2][d] + ssum[q * 4 + 3][d];
    float rm = fmaxf(fmaxf(smax[q * 4 + 0][d], smax[q * 4 + 1][d]),
                     fmaxf(smax[q * 4 + 2][d], smax[q * 4 + 3][d]));
    __syncthreads();
    ssum[q][d] = rs;
    smax[q][d] = rm;
    __syncthreads();
    if (q == 0) {
        ws_sum[(b * SPLIT + sp) * D + d] =
            ssum[0][d] + ssum[1][d] + ssum[2][d] + ssum[3][d];
    } else if (q == 1) {
        ws_max[(b * SPLIT + sp) * D + d] =
            fmaxf(fmaxf(smax[0][d], smax[1][d]), fmaxf(smax[2][d], smax[3][d]));
    }
}

__global__ __launch_bounds__(1024) void mlp_kernel(
    const float* __restrict__ ws_sum, const float* __restrict__ ws_max,
    const float* __restrict__ graph_emb, const float* __restrict__ meta,
    const float* __restrict__ sg_w1, const float* __restrict__ sg_b1,
    const float* __restrict__ sg_g,  const float* __restrict__ sg_bt,
    const float* __restrict__ sg_w2, const float* __restrict__ sg_b2,
    const float* __restrict__ mf_w1, const float* __restrict__ mf_b1,
    const float* __restrict__ mf_g,  const float* __restrict__ mf_bt,
    const float* __restrict__ mf_w2, const float* __restrict__ mf_b2,
    const float* __restrict__ cx_w1, const float* __restrict__ cx_b1,
    const float* __restrict__ cx_w2, const float* __restrict__ cx_b2,
    float* __restrict__ out)
{
    const int b = blockIdx.x;
    const int t = threadIdx.x;
    const int q = t >> 7;    // 0..7
    const int d = t & 127;

    __shared__ float xbuf[2 * D];
    __shared__ float pbuf[QS][D];
    __shared__ float hbufA[D];
    __shared__ float hbufB[D];
    __shared__ float red_a[D], red_b[D], red_c[D], red_d[D];
    __shared__ float stats[4];

    // ---- combine 8 pool partials: q0/q1 sum halves, q2/q3 max halves
    {
        float acc;
        if (q == 0 || q == 1) {
            acc = 0.f;
            const int s0 = q * 4;
            #pragma unroll
            for (int sp = s0; sp < s0 + 4; ++sp)
                acc += ws_sum[(b * SPLIT + sp) * D + d];
        } else if (q == 2 || q == 3) {
            acc = -INFINITY;
            const int s0 = (q - 2) * 4;
            #pragma unroll
            for (int sp = s0; sp < s0 + 4; ++sp)
                acc = fmaxf(acc, ws_max[(b * SPLIT + sp) * D + d]);
        } else acc = 0.f;
        pbuf[q][d] = acc;
        __syncthreads();
        if (q == 0)      xbuf[d]     = pbuf[0][d] + pbuf[1][d];
        else if (q == 1) xbuf[D + d] = fmaxf(pbuf[2][d], pbuf[3][d]);
        __syncthreads();
    }

    // ---- GEMV1 for sg (q<4) and mf (q>=4) in parallel
    {
        float acc = 0.f;
        if (q < 4) {
            const int k0 = q * 64;
            #pragma unroll 8
            for (int kk = 0; kk < 64; ++kk)
                acc = fmaf(xbuf[k0 + kk], sg_w1[(k0 + kk) * D + d], acc);
        } else {
            const int k0 = (q - 4) * 4;
            #pragma unroll
            for (int kk = 0; kk < 4; ++kk)
                acc = fmaf(meta[b * MM + k0 + kk], mf_w1[(k0 + kk) * D + d], acc);
        }
        pbuf[q][d] = acc;
        __syncthreads();
    }

    // ---- combine + fused LN (sum & sumsq one pass), both branches in parallel
    float h_sg = 0.f, h_mf = 0.f;
    if (q == 0) {
        h_sg = pbuf[0][d] + pbuf[1][d] + pbuf[2][d] + pbuf[3][d] + sg_b1[d];
        red_a[d] = h_sg; red_b[d] = h_sg * h_sg;
    } else if (q == 1) {
        h_mf = pbuf[4][d] + pbuf[5][d] + pbuf[6][d] + pbuf[7][d] + mf_b1[d];
        red_c[d] = h_mf; red_d[d] = h_mf * h_mf;
    }
    __syncthreads();
    if (t < 64) {
        float v1 = red_a[t] + red_a[t + 64];
        float v2 = red_b[t] + red_b[t + 64];
        #pragma unroll
        for (int off = 32; off; off >>= 1) {
            v1 += __shfl_xor(v1, off, 64);
            v2 += __shfl_xor(v2, off, 64);
        }
        if (t == 0) { stats[0] = v1 * (1.f / D); stats[1] = v2 * (1.f / D); }
    } else if (t < 128) {
        const int l = t - 64;
        float v1 = red_c[l] + red_c[l + 64];
        float v2 = red_d[l] + red_d[l + 64];
        #pragma unroll
        for (int off = 32; off; off >>= 1) {
            v1 += __shfl_xor(v1, off, 64);
            v2 += __shfl_xor(v2, off, 64);
        }
        if (l == 0) { stats[2] = v1 * (1.f / D); stats[3] = v2 * (1.f / D); }
    }
    __syncthreads();
    if (q == 0) {
        float mu = stats[0], var = stats[1] - mu * mu;
        hbufA[d] = gelu_f((h_sg - mu) * rsqrtf(var + 1e-5f) * sg_g[d] + sg_bt[d]);
    } else if (q == 1) {
        float mu = stats[2], var = stats[3] - mu * mu;
        hbufB[d] = gelu_f((h_mf - mu) * rsqrtf(var + 1e-5f) * mf_g[d] + mf_bt[d]);
    }
    __syncthreads();

    // ---- GEMV2 for sg (q<4) and mf (q>=4) in parallel
    {
        float acc = 0.f;
        if (q < 4) {
            const int k0 = q * 32;
            #pragma unroll 8
            for (int kk = 0; kk < 32; ++kk)
                acc = fmaf(hbufA[k0 + kk], sg_w2[(k0 + kk) * D + d], acc);
        } else {
            const int k0 = (q - 4) * 32;
            #pragma unroll 8
            for (int kk = 0; kk < 32; ++kk)
                acc = fmaf(hbufB[k0 + kk], mf_w2[(k0 + kk) * D + d], acc);
        }
        pbuf[q][d] = acc;
        __syncthreads();
        if (q == 0) {
            float sg = sg_b2[d] + mf_b2[d];
            #pragma unroll
            for (int r = 0; r < QS; ++r) sg += pbuf[r][d];
            out[b * D + d] = sg;
            xbuf[d] = sg;
        } else if (q == 1) {
            xbuf[D + d] = graph_emb[b * D + d];
        }
        __syncthreads();
    }

    // ---- cx GEMV1 (8-way) -> GELU
    {
        float acc = 0.f;
        const int k0 = q * 32;
        #pragma unroll 8
        for (int kk = 0; kk < 32; ++kk)
            acc = fmaf(xbuf[k0 + kk], cx_w1[(k0 + kk) * D + d], acc);
        pbuf[q][d] = acc;
        __syncthreads();
        if (q == 0) {
            float h = cx_b1[d];
            #pragma unroll
            for (int r = 0; r < QS; ++r) h += pbuf[r][d];
            hbufA[d] = gelu_f(h);
        }
        __syncthreads();
    }

    // ---- cx GEMV2 (8-way) -> ctxt output
    {
        float acc = 0.f;
        const int k0 = q * 16;
        #pragma unroll 8
        for (int kk = 0; kk < 16; ++kk)
            acc = fmaf(hbufA[k0 + kk], cx_w2[(k0 + kk) * D + d], acc);
        pbuf[q][d] = acc;
        __syncthreads();
        if (q == 0) {
            float o = cx_b2[d];
            #pragma unroll
            for (int r = 0; r < QS; ++r) o += pbuf[r][d];
            out[BS * D + b * D + d] = o;
        }
    }
}

extern "C" void kernel_launch(void* const* d_in, const int* in_sizes, int n_in,
                              void* d_out, int out_size, void* d_ws, size_t ws_size,
                              hipStream_t stream) {
    const float* node_emb  = (const float*)d_in[0];
    const float* graph_emb = (const float*)d_in[1];
    const int*   sg_idx    = (const int*)d_in[2];
    const float* meta      = (const float*)d_in[3];
    const float* sg_w1 = (const float*)d_in[4];
    const float* sg_b1 = (const float*)d_in[5];
    const float* sg_g  = (const float*)d_in[6];
    const float* sg_bt = (const float*)d_in[7];
    const float* sg_w2 = (const float*)d_in[8];
    const float* sg_b2 = (const float*)d_in[9];
    const float* mf_w1 = (const float*)d_in[10];
    const float* mf_b1 = (const float*)d_in[11];
    const float* mf_g  = (const float*)d_in[12];
    const float* mf_bt = (const float*)d_in[13];
    const float* mf_w2 = (const float*)d_in[14];
    const float* mf_b2 = (const float*)d_in[15];
    const float* cx_w1 = (const float*)d_in[16];
    const float* cx_b1 = (const float*)d_in[17];
    const float* cx_w2 = (const float*)d_in[18];
    const float* cx_b2 = (const float*)d_in[19];

    float* out    = (float*)d_out;
    float* ws     = (float*)d_ws;
    float* ws_sum = ws;                        // BS*SPLIT*D floats
    float* ws_max = ws + BS * SPLIT * D;       // BS*SPLIT*D floats (512 KB total)

    pool_kernel<<<BS * SPLIT, 512, 0, stream>>>(node_emb, sg_idx, ws_sum, ws_max);
    mlp_kernel<<<BS, 1024, 0, stream>>>(ws_sum, ws_max, graph_emb, meta,
        sg_w1, sg_b1, sg_g, sg_bt, sg_w2, sg_b2,
        mf_w1, mf_b1, mf_g, mf_bt, mf_w2, mf_b2,
        cx_w1, cx_b1, cx_w2, cx_b2, out);
}